// Round 1
// baseline (93.444 us; speedup 1.0000x reference)
//
#include <hip/hip_runtime.h>

// Spectral conv via folded constant operators:
//   out = Re( ((x · G) ⊙-mixed-by-W) · K )
// G[4096][64]  = interp(t-grid -> cheb nodes) ∘ quadrature ∘ exp(-2πi m t)
// K[64][4096]  = hat-interp(freq grid) ∘ f-quadrature ∘ exp(+2πi f t)
// Both are input-independent; rebuilt on device each launch (graph-safe).

#define NN    4096
#define BB    8
#define CINC  64
#define COUTC 64
#define LSEG  100
#define MCH   20
#define LM    2000

#define PI_D      3.14159265358979323846
#define TWO_PI_D  6.28318530717958647692

// ws layout (float offsets). Total 1187840 floats = ~4.53 MB.
#define OFF_ND   0         // node[20]
#define OFF_CW   32        // cc-weights[20] (endpoints halved)
#define OFF_TQ   64        // t quadrature nodes [2000]
#define OFF_WQ   2064      // t quadrature weights [2000]
#define OFF_IQ   4064      // interp index [2000] (int)
#define OFF_AL   6064      // interp alpha [2000]
#define OFF_GRE  8192      // G real [4096*64]
#define OFF_GIM  270336
#define OFF_KRE  532480    // K real [64*4096]
#define OFF_KIM  794624
#define OFF_XRE  1056768   // X real [512*64]
#define OFF_XIM  1089536
#define OFF_YRE  1122304   // Y real [512*64]
#define OFF_YIM  1155072

// ---------- setup: Clenshaw-Curtis nodes/weights + interp tables ----------
__global__ void k_nodes(float* __restrict__ ws) {
    int q = blockIdx.x * 256 + threadIdx.x;
    if (q >= LM) return;
    int l = q / MCH, k = q - l * MCH;
    double node = cos(PI_D * (double)k / 19.0);
    double v = 1.0;
    for (int j = 1; j <= 9; ++j)
        v -= 2.0 / (4.0 * j * j - 1.0) * cos(TWO_PI_D * (double)(j * k) / 19.0);
    double w = 2.0 * v / 19.0;
    if (k == 0 || k == 19) w *= 0.5;
    double tq = ((double)l + 0.5) / 100.0 + 0.005 * node;   // h = 0.5/L = 0.005
    double wq = 0.005 * w;
    double s = tq * 4095.0;
    int i = (int)floor(s);
    if (i < 0) i = 0;
    if (i > 4094) i = 4094;
    double a = s - (double)i;
    if (a < 0.0) a = 0.0;
    if (a > 1.0) a = 1.0;
    ws[OFF_TQ + q] = (float)tq;
    ws[OFF_WQ + q] = (float)wq;
    ((int*)ws)[OFF_IQ + q] = i;
    ws[OFF_AL + q] = (float)a;
    if (q < 20) { ws[OFF_ND + q] = (float)node; ws[OFF_CW + q] = (float)w; }
}

// ---------- setup: G = interp^T · (wts * exp(-2πi m t_q)), scatter-add ----------
__global__ void k_setupG(float* __restrict__ ws) {
    int idx = blockIdx.x * 256 + threadIdx.x;   // q*64 + m
    if (idx >= LM * 64) return;
    int q = idx >> 6, m = idx & 63;
    double tq = (double)ws[OFF_TQ + q];
    double wq = (double)ws[OFF_WQ + q];
    // phase/2π = -m*tq ; reduce in double, evaluate in float
    double r = -(double)m * tq;
    r -= floor(r);
    float th = (float)(r * TWO_PI_D);
    float sv, cv;
    __sincosf(th, &sv, &cv);
    float er = (float)wq * cv, ei = (float)wq * sv;
    int i = ((int*)ws)[OFF_IQ + q];
    float a = ws[OFF_AL + q];
    atomicAdd(&ws[OFF_GRE + i * 64 + m], (1.0f - a) * er);
    atomicAdd(&ws[OFF_GRE + (i + 1) * 64 + m], a * er);
    atomicAdd(&ws[OFF_GIM + i * 64 + m], (1.0f - a) * ei);
    atomicAdd(&ws[OFF_GIM + (i + 1) * 64 + m], a * ei);
}

// ---------- setup: K[m][j] = Σ_q hat(f_q-m)·wf_q·exp(2πi f_q t_j) ----------
// Only segments l=49..51 have nodes with |f_q - m| < 1 for m in [0,64).
__global__ void k_setupK(float* __restrict__ ws) {
    int idx = blockIdx.x * 256 + threadIdx.x;   // m*4096 + j
    if (idx >= 64 * NN) return;
    int m = idx >> 12, j = idx & (NN - 1);
    double tj = (double)j / 4095.0;
    double ar = 0.0, ai = 0.0;
    for (int l = 48; l <= 52; ++l) {
        double fc = -2048.0 + ((double)l + 0.5) * 40.95;   // (fb-fa)/L = 40.95
        for (int k = 0; k < 20; ++k) {
            double fq = fc + 20.475 * (double)ws[OFF_ND + k];  // hf = 20.475
            double u = fq - (double)m;
            double au = fabs(u);
            if (au < 1.0) {
                double wgt = (1.0 - au) * 20.475 * (double)ws[OFF_CW + k];
                double r = fq * tj;            // phase/2π
                r -= floor(r);
                float th = (float)(r * TWO_PI_D);
                float sv, cv;
                __sincosf(th, &sv, &cv);
                ar += wgt * (double)cv;
                ai += wgt * (double)sv;
            }
        }
    }
    ws[OFF_KRE + idx] = (float)ar;
    ws[OFF_KIM + idx] = (float)ai;
}

// ---------- stage 1: X[bc][m] = Σ_k x[bc][k] * G[k][m]  (complex G) ----------
// grid: (32 k-chunks of 128, 8 bc-chunks of 64); partials via atomicAdd (X zeroed).
__global__ __launch_bounds__(256) void k_stage1(const float* __restrict__ x,
                                                float* __restrict__ ws) {
    __shared__ __align__(16) float xt[64][65];
    __shared__ __align__(16) float gt[2][64][64];
    const int t = threadIdx.x;
    const int kc = blockIdx.x;
    const int cc = blockIdx.y;
    const int mg = t & 15, bg = t >> 4;
    float aR[4][4] = {{0.f}}, aI[4][4] = {{0.f}};
    for (int kt2 = 0; kt2 < 2; ++kt2) {
        const int k0 = kc * 128 + kt2 * 64;
        __syncthreads();
        for (int i = t; i < 64 * 64; i += 256) {
            int r = i >> 6, k = i & 63;
            xt[r][k] = x[(size_t)(cc * 64 + r) * NN + k0 + k];
        }
        for (int i = t; i < 64 * 64; i += 256) {
            int k = i >> 6, m = i & 63;
            gt[0][k][m] = ws[OFF_GRE + (size_t)(k0 + k) * 64 + m];
            gt[1][k][m] = ws[OFF_GIM + (size_t)(k0 + k) * 64 + m];
        }
        __syncthreads();
        for (int k = 0; k < 64; ++k) {
            const float4 gr = *(const float4*)&gt[0][k][mg * 4];
            const float4 gi = *(const float4*)&gt[1][k][mg * 4];
#pragma unroll
            for (int p = 0; p < 4; ++p) {
                const float xv = xt[bg * 4 + p][k];
                aR[p][0] += xv * gr.x; aR[p][1] += xv * gr.y;
                aR[p][2] += xv * gr.z; aR[p][3] += xv * gr.w;
                aI[p][0] += xv * gi.x; aI[p][1] += xv * gi.y;
                aI[p][2] += xv * gi.z; aI[p][3] += xv * gi.w;
            }
        }
    }
#pragma unroll
    for (int p = 0; p < 4; ++p)
#pragma unroll
        for (int v = 0; v < 4; ++v) {
            const int bc = cc * 64 + bg * 4 + p;
            const int m = mg * 4 + v;
            atomicAdd(&ws[OFF_XRE + bc * 64 + m], aR[p][v]);
            atomicAdd(&ws[OFF_XIM + bc * 64 + m], aI[p][v]);
        }
}

// ---------- stage 2: Y[b][o][m] = Σ_i X[b][i][m] * (Wr + iWi)[i][o][m] ----------
__global__ void k_mix(const float* __restrict__ wr, const float* __restrict__ wi,
                      float* __restrict__ ws) {
    int idx = blockIdx.x * 256 + threadIdx.x;   // b*4096 + o*64 + m
    if (idx >= BB * COUTC * 64) return;
    int m = idx & 63, o = (idx >> 6) & 63, b = idx >> 12;
    float yr = 0.f, yi = 0.f;
    for (int i = 0; i < CINC; ++i) {
        float xr = ws[OFF_XRE + (size_t)(b * 64 + i) * 64 + m];
        float xi = ws[OFF_XIM + (size_t)(b * 64 + i) * 64 + m];
        float a = wr[(size_t)(i * 64 + o) * 64 + m];
        float c = wi[(size_t)(i * 64 + o) * 64 + m];
        yr += xr * a - xi * c;
        yi += xr * c + xi * a;
    }
    ws[OFF_YRE + idx] = yr;
    ws[OFF_YIM + idx] = yi;
}

// ---------- stage 3: out[pair][j] = Σ_m Yre*Kre - Yim*Kim ----------
// grid: (64 j-tiles of 64, 8 pair-chunks of 64); thread tile 4 pairs × 4 j.
__global__ __launch_bounds__(256) void k_stage3(const float* __restrict__ ws,
                                                float* __restrict__ out) {
    __shared__ __align__(16) float kt[2][64][64];
    const int t = threadIdx.x;
    const int jt = blockIdx.x;
    const int pc = blockIdx.y;
    for (int i = t; i < 64 * 64; i += 256) {
        int m = i >> 6, jl = i & 63;
        kt[0][m][jl] = ws[OFF_KRE + (size_t)m * NN + jt * 64 + jl];
        kt[1][m][jl] = ws[OFF_KIM + (size_t)m * NN + jt * 64 + jl];
    }
    __syncthreads();
    const int jg = t & 15, pg = t >> 4;
    const float* Yre = ws + OFF_YRE + (size_t)(pc * 64 + pg * 4) * 64;
    const float* Yim = ws + OFF_YIM + (size_t)(pc * 64 + pg * 4) * 64;
    float acc[4][4] = {{0.f}};
    for (int m0 = 0; m0 < 64; m0 += 4) {
        float yr[4][4], yi[4][4];
#pragma unroll
        for (int p = 0; p < 4; ++p) {
            float4 a = *(const float4*)&Yre[p * 64 + m0];
            float4 b = *(const float4*)&Yim[p * 64 + m0];
            yr[p][0] = a.x; yr[p][1] = a.y; yr[p][2] = a.z; yr[p][3] = a.w;
            yi[p][0] = b.x; yi[p][1] = b.y; yi[p][2] = b.z; yi[p][3] = b.w;
        }
#pragma unroll
        for (int mm = 0; mm < 4; ++mm) {
            const float4 kr = *(const float4*)&kt[0][m0 + mm][jg * 4];
            const float4 ki = *(const float4*)&kt[1][m0 + mm][jg * 4];
#pragma unroll
            for (int p = 0; p < 4; ++p) {
                acc[p][0] += yr[p][mm] * kr.x - yi[p][mm] * ki.x;
                acc[p][1] += yr[p][mm] * kr.y - yi[p][mm] * ki.y;
                acc[p][2] += yr[p][mm] * kr.z - yi[p][mm] * ki.z;
                acc[p][3] += yr[p][mm] * kr.w - yi[p][mm] * ki.w;
            }
        }
    }
#pragma unroll
    for (int p = 0; p < 4; ++p) {
        float4 r;
        r.x = acc[p][0]; r.y = acc[p][1]; r.z = acc[p][2]; r.w = acc[p][3];
        *(float4*)&out[(size_t)(pc * 64 + pg * 4 + p) * NN + jt * 64 + jg * 4] = r;
    }
}

extern "C" void kernel_launch(void* const* d_in, const int* in_sizes, int n_in,
                              void* d_out, int out_size, void* d_ws, size_t ws_size,
                              hipStream_t stream) {
    const float* x  = (const float*)d_in[0];
    const float* wr = (const float*)d_in[1];
    const float* wi = (const float*)d_in[2];
    float* out = (float*)d_out;
    float* ws  = (float*)d_ws;
    // needs ~4.53 MB of workspace
    (void)in_sizes; (void)n_in; (void)out_size; (void)ws_size;

    // zero G (atomic scatter target) and X (atomic partial target)
    hipMemsetAsync(ws + OFF_GRE, 0, (size_t)2 * 262144 * sizeof(float), stream);
    hipMemsetAsync(ws + OFF_XRE, 0, (size_t)2 * 32768 * sizeof(float), stream);

    k_nodes<<<8, 256, 0, stream>>>(ws);
    k_setupG<<<(LM * 64) / 256, 256, 0, stream>>>(ws);
    k_setupK<<<(64 * NN) / 256, 256, 0, stream>>>(ws);
    k_stage1<<<dim3(32, 8), 256, 0, stream>>>(x, ws);
    k_mix<<<BB * COUTC * 64 / 256, 256, 0, stream>>>(wr, wi, ws);
    k_stage3<<<dim3(64, 8), 256, 0, stream>>>(ws, out);
}

// Round 2
// 81.822 us; speedup vs baseline: 1.1420x; 1.1420x over previous
//
#include <hip/hip_runtime.h>

// Spectral conv via folded constant operators:
//   out = Re( ((x · G) ⊙-mixed-by-W) · K )
// G[4096][64], K[64][4096] are input-independent; rebuilt each launch.
// v2: no global atomics anywhere (round-1 showed 32MB/dispatch HBM write-through
// from device-scope atomicAdd = the entire stage1 cost). Split-K partials +
// separate reduce instead.

#define NN    4096
#define BB    8
#define CINC  64
#define COUTC 64
#define LSEG  100
#define MCH   20
#define LM    2000

#define PI_D      3.14159265358979323846
#define TWO_PI_D  6.28318530717958647692

// ws layout (float offsets)
#define OFF_GRE  8192      // G real [4096*64]
#define OFF_GIM  270336
#define OFF_KRE  532480    // K real [64*4096]
#define OFF_KIM  794624
#define OFF_XRE  1056768   // X real [512*64]
#define OFF_XIM  1089536
#define OFF_YRE  1122304   // Y real [512*64]
#define OFF_YIM  1155072
#define OFF_P    1187840   // split-K partials [KC][512][128]

// ---------- fused setup: G rows (gather, no atomics) + K ----------
// grid: 1024 blocks (G: 4 rows each) + 1024 blocks (K), 256 threads.
__global__ void k_setup(float* __restrict__ ws) {
    const int t = threadIdx.x;
    if (blockIdx.x < 1024) {
        // ---- G part: rows k = blockIdx.x*4 .. +3 ----
        __shared__ float q_t[4][24];   // (float)tq per contribution
        __shared__ float q_c[4][24];   // coef * wq
        __shared__ int   q_n[4];
        const int r = t >> 6;          // local row 0..3
        const int lane = t & 63;
        const int k = blockIdx.x * 4 + r;
        if (lane == 0) q_n[r] = 0;
        __syncthreads();
        if (lane < 60) {
            // candidate segments l0-1..l0+1, 20 cheb nodes each
            int lc = (int)floor(((double)k + 0.5) / 4095.0 * 100.0);
            int l = lc - 1 + lane / 20;
            int j = lane % 20;
            if (l >= 0 && l < 100) {
                double node = cos(PI_D * (double)j / 19.0);
                double tq = ((double)l + 0.5) / 100.0 + 0.005 * node;
                double s = tq * 4095.0;
                int i = (int)floor(s);
                if (i < 0) i = 0;
                if (i > 4094) i = 4094;
                double a = s - (double)i;
                if (a < 0.0) a = 0.0;
                if (a > 1.0) a = 1.0;
                float coef = 0.f;
                if (i == k) coef = (float)(1.0 - a);
                else if (i == k - 1) coef = (float)a;
                if (coef != 0.f) {
                    double v = 1.0;
                    for (int jj = 1; jj <= 9; ++jj)
                        v -= 2.0 / (4.0 * jj * jj - 1.0) *
                             cos(TWO_PI_D * (double)(jj * j) / 19.0);
                    double w = 2.0 * v / 19.0;
                    if (j == 0 || j == 19) w *= 0.5;
                    float wq = (float)(0.005 * w);
                    int slot = atomicAdd(&q_n[r], 1);   // LDS atomic: cheap
                    q_t[r][slot] = (float)tq;
                    q_c[r][slot] = coef * wq;
                }
            }
        }
        __syncthreads();
        const int m = lane;
        const int n = q_n[r];
        float gr = 0.f, gi = 0.f;
        for (int s = 0; s < n; ++s) {
            double tq = (double)q_t[r][s];
            double rr = -(double)m * tq;        // phase / 2pi
            rr -= floor(rr);
            float th = (float)(rr * TWO_PI_D);
            float sv, cv;
            __sincosf(th, &sv, &cv);
            gr += q_c[r][s] * cv;
            gi += q_c[r][s] * sv;
        }
        ws[OFF_GRE + (size_t)k * 64 + m] = gr;
        ws[OFF_GIM + (size_t)k * 64 + m] = gi;
    } else {
        // ---- K part: K[m][j] = sum_q hat(f_q-m) wf_q exp(2pi i f_q t_j) ----
        __shared__ float nd[20], cwf[20];
        if (t < 20) {
            double node = cos(PI_D * (double)t / 19.0);
            double v = 1.0;
            for (int jj = 1; jj <= 9; ++jj)
                v -= 2.0 / (4.0 * jj * jj - 1.0) *
                     cos(TWO_PI_D * (double)(jj * t) / 19.0);
            double w = 2.0 * v / 19.0;
            if (t == 0 || t == 19) w *= 0.5;
            nd[t] = (float)node;
            cwf[t] = (float)w;
        }
        __syncthreads();
        int idx = (blockIdx.x - 1024) * 256 + t;    // m*4096 + j
        int m = idx >> 12, j = idx & (NN - 1);
        double tj = (double)j / 4095.0;
        double ar = 0.0, ai = 0.0;
        for (int l = 48; l <= 52; ++l) {
            double fc = -2048.0 + ((double)l + 0.5) * 40.95;
            for (int kk = 0; kk < 20; ++kk) {
                double fq = fc + 20.475 * (double)nd[kk];
                double u = fq - (double)m;
                double au = fabs(u);
                if (au < 1.0) {
                    double wgt = (1.0 - au) * 20.475 * (double)cwf[kk];
                    double rr = fq * tj;
                    rr -= floor(rr);
                    float th = (float)(rr * TWO_PI_D);
                    float sv, cv;
                    __sincosf(th, &sv, &cv);
                    ar += wgt * (double)cv;
                    ai += wgt * (double)sv;
                }
            }
        }
        ws[OFF_KRE + idx] = (float)ar;
        ws[OFF_KIM + idx] = (float)ai;
    }
}

// ---------- stage 1: split-K partials P[kc][bc][128], no atomics ----------
// grid (KC, 8), 256 thr; each block: 64 bc x 64 m, SUBT k-subtiles of 64.
__global__ __launch_bounds__(256) void k_stage1(const float* __restrict__ x,
                                                const float* __restrict__ ws,
                                                float* __restrict__ P, int SUBT) {
    __shared__ __align__(16) float xt[64][68];
    __shared__ __align__(16) float gt[2][64][64];
    const int t = threadIdx.x;
    const int cc = blockIdx.y;
    const int mg = t & 15, bg = t >> 4;
    float aR[4][4] = {{0.f}}, aI[4][4] = {{0.f}};
    for (int st = 0; st < SUBT; ++st) {
        const int k0 = (blockIdx.x * SUBT + st) * 64;
        __syncthreads();
        for (int i = t; i < 64 * 64; i += 256) {
            int r = i >> 6, kk = i & 63;
            xt[r][kk] = x[(size_t)(cc * 64 + r) * NN + k0 + kk];
        }
        for (int i = t; i < 64 * 64; i += 256) {
            int kk = i >> 6, m = i & 63;
            gt[0][kk][m] = ws[OFF_GRE + (size_t)(k0 + kk) * 64 + m];
            gt[1][kk][m] = ws[OFF_GIM + (size_t)(k0 + kk) * 64 + m];
        }
        __syncthreads();
        for (int kq = 0; kq < 16; ++kq) {
            float4 xv[4];
#pragma unroll
            for (int p = 0; p < 4; ++p)
                xv[p] = *(const float4*)&xt[bg * 4 + p][kq * 4];
#pragma unroll
            for (int mm = 0; mm < 4; ++mm) {
                const float4 gr = *(const float4*)&gt[0][kq * 4 + mm][mg * 4];
                const float4 gi = *(const float4*)&gt[1][kq * 4 + mm][mg * 4];
#pragma unroll
                for (int p = 0; p < 4; ++p) {
                    const float xm = (mm == 0) ? xv[p].x : (mm == 1) ? xv[p].y
                                   : (mm == 2) ? xv[p].z : xv[p].w;
                    aR[p][0] += xm * gr.x; aR[p][1] += xm * gr.y;
                    aR[p][2] += xm * gr.z; aR[p][3] += xm * gr.w;
                    aI[p][0] += xm * gi.x; aI[p][1] += xm * gi.y;
                    aI[p][2] += xm * gi.z; aI[p][3] += xm * gi.w;
                }
            }
        }
    }
    // coalesced float4 stores of partials
#pragma unroll
    for (int p = 0; p < 4; ++p) {
        const size_t row = (size_t)blockIdx.x * 512 + cc * 64 + bg * 4 + p;
        float4 vr, vi;
        vr.x = aR[p][0]; vr.y = aR[p][1]; vr.z = aR[p][2]; vr.w = aR[p][3];
        vi.x = aI[p][0]; vi.y = aI[p][1]; vi.z = aI[p][2]; vi.w = aI[p][3];
        *(float4*)&P[row * 128 + mg * 4]      = vr;
        *(float4*)&P[row * 128 + 64 + mg * 4] = vi;
    }
}

// ---------- reduce: X = sum_kc P[kc] ----------
__global__ void k_reduce(float* __restrict__ ws, const float* __restrict__ P,
                         int KC) {
    int idx = blockIdx.x * 256 + threadIdx.x;    // 65536 = 512 bc * 128 col
    int bc = idx >> 7, col = idx & 127;
    float s = 0.f;
    for (int kc = 0; kc < KC; ++kc)
        s += P[((size_t)kc * 512 + bc) * 128 + col];
    if (col < 64) ws[OFF_XRE + (size_t)bc * 64 + col] = s;
    else          ws[OFF_XIM + (size_t)bc * 64 + col - 64] = s;
}

// ---------- stage 2: Y[b][o][m] = sum_i X[b][i][m] * (Wr + iWi)[i][o][m] ----------
__global__ void k_mix(const float* __restrict__ wr, const float* __restrict__ wi,
                      float* __restrict__ ws) {
    int idx = blockIdx.x * 256 + threadIdx.x;   // b*4096 + o*64 + m
    int m = idx & 63, o = (idx >> 6) & 63, b = idx >> 12;
    float yr = 0.f, yi = 0.f;
    for (int i = 0; i < CINC; ++i) {
        float xr = ws[OFF_XRE + (size_t)(b * 64 + i) * 64 + m];
        float xi = ws[OFF_XIM + (size_t)(b * 64 + i) * 64 + m];
        float a = wr[(size_t)(i * 64 + o) * 64 + m];
        float c = wi[(size_t)(i * 64 + o) * 64 + m];
        yr += xr * a - xi * c;
        yi += xr * c + xi * a;
    }
    ws[OFF_YRE + idx] = yr;
    ws[OFF_YIM + idx] = yi;
}

// ---------- stage 3: out[pair][j] = sum_m Yre*Kre - Yim*Kim ----------
__global__ __launch_bounds__(256) void k_stage3(const float* __restrict__ ws,
                                                float* __restrict__ out) {
    __shared__ __align__(16) float kt[2][64][64];
    const int t = threadIdx.x;
    const int jt = blockIdx.x;
    const int pc = blockIdx.y;
    for (int i = t; i < 64 * 64; i += 256) {
        int m = i >> 6, jl = i & 63;
        kt[0][m][jl] = ws[OFF_KRE + (size_t)m * NN + jt * 64 + jl];
        kt[1][m][jl] = ws[OFF_KIM + (size_t)m * NN + jt * 64 + jl];
    }
    __syncthreads();
    const int jg = t & 15, pg = t >> 4;
    const float* Yre = ws + OFF_YRE + (size_t)(pc * 64 + pg * 4) * 64;
    const float* Yim = ws + OFF_YIM + (size_t)(pc * 64 + pg * 4) * 64;
    float acc[4][4] = {{0.f}};
    for (int m0 = 0; m0 < 64; m0 += 4) {
        float yr[4][4], yi[4][4];
#pragma unroll
        for (int p = 0; p < 4; ++p) {
            float4 a = *(const float4*)&Yre[p * 64 + m0];
            float4 b = *(const float4*)&Yim[p * 64 + m0];
            yr[p][0] = a.x; yr[p][1] = a.y; yr[p][2] = a.z; yr[p][3] = a.w;
            yi[p][0] = b.x; yi[p][1] = b.y; yi[p][2] = b.z; yi[p][3] = b.w;
        }
#pragma unroll
        for (int mm = 0; mm < 4; ++mm) {
            const float4 kr = *(const float4*)&kt[0][m0 + mm][jg * 4];
            const float4 ki = *(const float4*)&kt[1][m0 + mm][jg * 4];
#pragma unroll
            for (int p = 0; p < 4; ++p) {
                acc[p][0] += yr[p][mm] * kr.x - yi[p][mm] * ki.x;
                acc[p][1] += yr[p][mm] * kr.y - yi[p][mm] * ki.y;
                acc[p][2] += yr[p][mm] * kr.z - yi[p][mm] * ki.z;
                acc[p][3] += yr[p][mm] * kr.w - yi[p][mm] * ki.w;
            }
        }
    }
#pragma unroll
    for (int p = 0; p < 4; ++p) {
        float4 r;
        r.x = acc[p][0]; r.y = acc[p][1]; r.z = acc[p][2]; r.w = acc[p][3];
        *(float4*)&out[(size_t)(pc * 64 + pg * 4 + p) * NN + jt * 64 + jg * 4] = r;
    }
}

extern "C" void kernel_launch(void* const* d_in, const int* in_sizes, int n_in,
                              void* d_out, int out_size, void* d_ws, size_t ws_size,
                              hipStream_t stream) {
    const float* x  = (const float*)d_in[0];
    const float* wr = (const float*)d_in[1];
    const float* wi = (const float*)d_in[2];
    float* out = (float*)d_out;
    float* ws  = (float*)d_ws;
    (void)in_sizes; (void)n_in; (void)out_size;

    // pick split-K factor by available workspace (deterministic given sizes)
    const size_t fixed_bytes = (size_t)OFF_P * 4;
    int KC, SUBT;
    if (ws_size >= fixed_bytes + 64ull * 512 * 128 * 4)      { KC = 64; SUBT = 1; }
    else if (ws_size >= fixed_bytes + 8ull * 512 * 128 * 4)  { KC = 8;  SUBT = 8; }
    else                                                     { KC = 2;  SUBT = 32; }
    float* P = ws + OFF_P;

    k_setup<<<2048, 256, 0, stream>>>(ws);
    k_stage1<<<dim3(KC, 8), 256, 0, stream>>>(x, ws, P, SUBT);
    k_reduce<<<256, 256, 0, stream>>>(ws, P, KC);
    k_mix<<<BB * COUTC * 64 / 256, 256, 0, stream>>>(wr, wi, ws);
    k_stage3<<<dim3(64, 8), 256, 0, stream>>>(ws, out);
}

// Round 3
// 67.427 us; speedup vs baseline: 1.3859x; 1.2135x over previous
//
#include <hip/hip_runtime.h>

// Spectral conv via folded constant operators:
//   out = Re( ((x · G) ⊙-mixed-by-W) · K )
// G[4096][64], K[64][4096] input-independent; rebuilt each launch (graph-safe).
// v3: float4 everywhere (staging + reduce), K-setup via per-m node lists,
// raw HW sin/cos in revolutions (no libm range reduction), 4-way split reduce.

#define NN    4096
#define BB    8
#define CINC  64
#define COUTC 64

#define PI_D      3.14159265358979323846
#define TWO_PI_D  6.28318530717958647692

// ws layout (float offsets)
#define OFF_GRE  8192      // G real [4096*64]
#define OFF_GIM  270336
#define OFF_KRE  532480    // K real [64*4096]
#define OFF_KIM  794624
#define OFF_XRE  1056768   // X real [512*64]
#define OFF_XIM  1089536
#define OFF_YRE  1122304   // Y real [512*64]
#define OFF_YIM  1155072
#define OFF_P    1187840   // split-K partials [KC][512][128]

__device__ __forceinline__ float hw_sin_rev(float r) { return __builtin_amdgcn_sinf(r); }
__device__ __forceinline__ float hw_cos_rev(float r) { return __builtin_amdgcn_cosf(r); }

// ---------- fused setup ----------
// blocks [0,1024): G rows (4 per block, gather, no global atomics)
// blocks [1024,1088): K rows (1 m per block, per-m contributing-node list)
__global__ void k_setup(float* __restrict__ ws) {
    const int t = threadIdx.x;
    if (blockIdx.x < 1024) {
        // ---- G part: rows k = blockIdx.x*4 .. +3 ----
        __shared__ float q_t[4][24];   // tq per contribution
        __shared__ float q_c[4][24];   // coef * wq
        __shared__ int   q_n[4];
        const int r = t >> 6;
        const int lane = t & 63;
        const int k = blockIdx.x * 4 + r;
        if (lane == 0) q_n[r] = 0;
        __syncthreads();
        if (lane < 60) {
            int lc = (int)floor(((double)k + 0.5) / 4095.0 * 100.0);
            int l = lc - 1 + lane / 20;
            int j = lane % 20;
            if (l >= 0 && l < 100) {
                double node = cos(PI_D * (double)j / 19.0);
                double tq = ((double)l + 0.5) / 100.0 + 0.005 * node;
                double s = tq * 4095.0;
                int i = (int)floor(s);
                if (i < 0) i = 0;
                if (i > 4094) i = 4094;
                double a = s - (double)i;
                if (a < 0.0) a = 0.0;
                if (a > 1.0) a = 1.0;
                float coef = 0.f;
                if (i == k) coef = (float)(1.0 - a);
                else if (i == k - 1) coef = (float)a;
                if (coef != 0.f) {
                    double v = 1.0;
                    for (int jj = 1; jj <= 9; ++jj)
                        v -= 2.0 / (4.0 * jj * jj - 1.0) *
                             cos(TWO_PI_D * (double)(jj * j) / 19.0);
                    double w = 2.0 * v / 19.0;
                    if (j == 0 || j == 19) w *= 0.5;
                    int slot = atomicAdd(&q_n[r], 1);   // LDS atomic
                    q_t[r][slot] = (float)tq;
                    q_c[r][slot] = coef * (float)(0.005 * w);
                }
            }
        }
        __syncthreads();
        const int m = lane;
        const int n = q_n[r];
        float gr = 0.f, gi = 0.f;
        for (int s = 0; s < n; ++s) {
            double rr = -(double)m * (double)q_t[r][s];  // phase / 2pi
            rr -= floor(rr);
            float rf = (float)rr;
            gr += q_c[r][s] * hw_cos_rev(rf);
            gi += q_c[r][s] * hw_sin_rev(rf);
        }
        ws[OFF_GRE + (size_t)k * 64 + m] = gr;
        ws[OFF_GIM + (size_t)k * 64 + m] = gi;
    } else {
        // ---- K part: one m per block. Contributing f-nodes: |fq-m|<1,
        // only segments l=49..51 overlap (-1,64). Build list once, then j-loop.
        const int m = blockIdx.x - 1024;
        __shared__ double sfq[16];
        __shared__ float  swt[16];
        __shared__ int    sn;
        if (t == 0) sn = 0;
        __syncthreads();
        if (t < 60) {
            int l = 49 + t / 20;
            int kk = t % 20;
            double node = cos(PI_D * (double)kk / 19.0);
            double fc = -2048.0 + ((double)l + 0.5) * 40.95;
            double fq = fc + 20.475 * node;
            double au = fabs(fq - (double)m);
            if (au < 1.0) {
                double v = 1.0;
                for (int jj = 1; jj <= 9; ++jj)
                    v -= 2.0 / (4.0 * jj * jj - 1.0) *
                         cos(TWO_PI_D * (double)(jj * kk) / 19.0);
                double w = 2.0 * v / 19.0;
                if (kk == 0 || kk == 19) w *= 0.5;
                int slot = atomicAdd(&sn, 1);
                sfq[slot] = fq;
                swt[slot] = (float)((1.0 - au) * 20.475 * w);
            }
        }
        __syncthreads();
        const int n = sn;
        for (int it = 0; it < 16; ++it) {
            int j = it * 256 + t;
            double tj = (double)j / 4095.0;
            float ar = 0.f, ai = 0.f;
            for (int s = 0; s < n; ++s) {
                double rr = sfq[s] * tj;       // phase / 2pi
                rr -= floor(rr);
                float rf = (float)rr;
                ar += swt[s] * hw_cos_rev(rf);
                ai += swt[s] * hw_sin_rev(rf);
            }
            ws[OFF_KRE + (size_t)m * NN + j] = ar;
            ws[OFF_KIM + (size_t)m * NN + j] = ai;
        }
    }
}

// ---------- stage 1: split-K partials P[kc][bc][128], float4 staging ----------
__global__ __launch_bounds__(256) void k_stage1(const float* __restrict__ x,
                                                const float* __restrict__ ws,
                                                float* __restrict__ P, int SUBT) {
    __shared__ __align__(16) float xt[64][68];     // 68*4 = 272 B row stride (16B-mult)
    __shared__ __align__(16) float gt[2][64][64];
    const int t = threadIdx.x;
    const int cc = blockIdx.y;
    const int mg = t & 15, bg = t >> 4;
    float aR[4][4] = {{0.f}}, aI[4][4] = {{0.f}};
    for (int st = 0; st < SUBT; ++st) {
        const int k0 = (blockIdx.x * SUBT + st) * 64;
        __syncthreads();
#pragma unroll
        for (int it = 0; it < 4; ++it) {           // x tile: 1024 float4
            int idx = it * 256 + t;
            int row = idx >> 4, c4 = idx & 15;
            *(float4*)&xt[row][c4 * 4] =
                *(const float4*)&x[(size_t)(cc * 64 + row) * NN + k0 + c4 * 4];
        }
#pragma unroll
        for (int it = 0; it < 8; ++it) {           // G tile: 2048 float4
            int idx = it * 256 + t;
            int part = idx >> 10, rem = idx & 1023;
            int row = rem >> 4, c4 = rem & 15;
            const size_t src = (part ? OFF_GIM : OFF_GRE) + (size_t)(k0 + row) * 64 + c4 * 4;
            *(float4*)&gt[part][row][c4 * 4] = *(const float4*)&ws[src];
        }
        __syncthreads();
        for (int kq = 0; kq < 16; ++kq) {
            float4 xv[4];
#pragma unroll
            for (int p = 0; p < 4; ++p)
                xv[p] = *(const float4*)&xt[bg * 4 + p][kq * 4];
#pragma unroll
            for (int mm = 0; mm < 4; ++mm) {
                const float4 gr = *(const float4*)&gt[0][kq * 4 + mm][mg * 4];
                const float4 gi = *(const float4*)&gt[1][kq * 4 + mm][mg * 4];
#pragma unroll
                for (int p = 0; p < 4; ++p) {
                    const float xm = (mm == 0) ? xv[p].x : (mm == 1) ? xv[p].y
                                   : (mm == 2) ? xv[p].z : xv[p].w;
                    aR[p][0] += xm * gr.x; aR[p][1] += xm * gr.y;
                    aR[p][2] += xm * gr.z; aR[p][3] += xm * gr.w;
                    aI[p][0] += xm * gi.x; aI[p][1] += xm * gi.y;
                    aI[p][2] += xm * gi.z; aI[p][3] += xm * gi.w;
                }
            }
        }
    }
#pragma unroll
    for (int p = 0; p < 4; ++p) {
        const size_t row = (size_t)blockIdx.x * 512 + cc * 64 + bg * 4 + p;
        float4 vr, vi;
        vr.x = aR[p][0]; vr.y = aR[p][1]; vr.z = aR[p][2]; vr.w = aR[p][3];
        vi.x = aI[p][0]; vi.y = aI[p][1]; vi.z = aI[p][2]; vi.w = aI[p][3];
        *(float4*)&P[row * 128 + mg * 4]      = vr;
        *(float4*)&P[row * 128 + 64 + mg * 4] = vi;
    }
}

// ---------- reduce: X = sum_kc P[kc], float4 + 4-way kc split ----------
// grid 256 blocks; block handles 64 float4 outputs; 4 kc-groups of KC/4.
__global__ __launch_bounds__(256) void k_reduce(float* __restrict__ ws,
                                                const float* __restrict__ P, int KC) {
    __shared__ float4 red[4][64];
    const int t = threadIdx.x;
    const int grp = t >> 6, o = t & 63;
    const int out_id = blockIdx.x * 64 + o;        // bc*32 + c4, 16384 total
    const float4* P4 = (const float4*)P;
    const int kpg = KC >> 2;
    float4 s = {0.f, 0.f, 0.f, 0.f};
    for (int kk = 0; kk < kpg; ++kk) {
        float4 v = P4[(size_t)(grp * kpg + kk) * 16384 + out_id];
        s.x += v.x; s.y += v.y; s.z += v.z; s.w += v.w;
    }
    red[grp][o] = s;
    __syncthreads();
    if (t < 64) {
        const int oid = blockIdx.x * 64 + t;
        float4 a = red[0][t], b = red[1][t], c = red[2][t], d = red[3][t];
        float4 r;
        r.x = (a.x + b.x) + (c.x + d.x);
        r.y = (a.y + b.y) + (c.y + d.y);
        r.z = (a.z + b.z) + (c.z + d.z);
        r.w = (a.w + b.w) + (c.w + d.w);
        int bc = oid >> 5, c4 = oid & 31;
        if (c4 < 16) *(float4*)&ws[OFF_XRE + (size_t)bc * 64 + c4 * 4] = r;
        else         *(float4*)&ws[OFF_XIM + (size_t)bc * 64 + (c4 - 16) * 4] = r;
    }
}

// ---------- stage 2: Y[b][o][m] = sum_i X[b][i][m] * (Wr + iWi)[i][o][m] ----------
__global__ void k_mix(const float* __restrict__ wr, const float* __restrict__ wi,
                      float* __restrict__ ws) {
    int idx = blockIdx.x * 256 + threadIdx.x;   // b*4096 + o*64 + m
    int m = idx & 63, o = (idx >> 6) & 63, b = idx >> 12;
    float yr = 0.f, yi = 0.f;
    for (int i = 0; i < CINC; ++i) {
        float xr = ws[OFF_XRE + (size_t)(b * 64 + i) * 64 + m];
        float xi = ws[OFF_XIM + (size_t)(b * 64 + i) * 64 + m];
        float a = wr[(size_t)(i * 64 + o) * 64 + m];
        float c = wi[(size_t)(i * 64 + o) * 64 + m];
        yr += xr * a - xi * c;
        yi += xr * c + xi * a;
    }
    ws[OFF_YRE + idx] = yr;
    ws[OFF_YIM + idx] = yi;
}

// ---------- stage 3: out[pair][j] = sum_m Yre*Kre - Yim*Kim ----------
__global__ __launch_bounds__(256) void k_stage3(const float* __restrict__ ws,
                                                float* __restrict__ out) {
    __shared__ __align__(16) float kt[2][64][64];
    const int t = threadIdx.x;
    const int jt = blockIdx.x;
    const int pc = blockIdx.y;
#pragma unroll
    for (int it = 0; it < 8; ++it) {               // K tile: 2048 float4
        int idx = it * 256 + t;
        int part = idx >> 10, rem = idx & 1023;
        int row = rem >> 4, c4 = rem & 15;
        const size_t src = (part ? OFF_KIM : OFF_KRE) + (size_t)row * NN + jt * 64 + c4 * 4;
        *(float4*)&kt[part][row][c4 * 4] = *(const float4*)&ws[src];
    }
    __syncthreads();
    const int jg = t & 15, pg = t >> 4;
    const float* Yre = ws + OFF_YRE + (size_t)(pc * 64 + pg * 4) * 64;
    const float* Yim = ws + OFF_YIM + (size_t)(pc * 64 + pg * 4) * 64;
    float acc[4][4] = {{0.f}};
    for (int m0 = 0; m0 < 64; m0 += 4) {
        float yr[4][4], yi[4][4];
#pragma unroll
        for (int p = 0; p < 4; ++p) {
            float4 a = *(const float4*)&Yre[p * 64 + m0];
            float4 b = *(const float4*)&Yim[p * 64 + m0];
            yr[p][0] = a.x; yr[p][1] = a.y; yr[p][2] = a.z; yr[p][3] = a.w;
            yi[p][0] = b.x; yi[p][1] = b.y; yi[p][2] = b.z; yi[p][3] = b.w;
        }
#pragma unroll
        for (int mm = 0; mm < 4; ++mm) {
            const float4 kr = *(const float4*)&kt[0][m0 + mm][jg * 4];
            const float4 ki = *(const float4*)&kt[1][m0 + mm][jg * 4];
#pragma unroll
            for (int p = 0; p < 4; ++p) {
                acc[p][0] += yr[p][mm] * kr.x - yi[p][mm] * ki.x;
                acc[p][1] += yr[p][mm] * kr.y - yi[p][mm] * ki.y;
                acc[p][2] += yr[p][mm] * kr.z - yi[p][mm] * ki.z;
                acc[p][3] += yr[p][mm] * kr.w - yi[p][mm] * ki.w;
            }
        }
    }
#pragma unroll
    for (int p = 0; p < 4; ++p) {
        float4 r;
        r.x = acc[p][0]; r.y = acc[p][1]; r.z = acc[p][2]; r.w = acc[p][3];
        *(float4*)&out[(size_t)(pc * 64 + pg * 4 + p) * NN + jt * 64 + jg * 4] = r;
    }
}

extern "C" void kernel_launch(void* const* d_in, const int* in_sizes, int n_in,
                              void* d_out, int out_size, void* d_ws, size_t ws_size,
                              hipStream_t stream) {
    const float* x  = (const float*)d_in[0];
    const float* wr = (const float*)d_in[1];
    const float* wi = (const float*)d_in[2];
    float* out = (float*)d_out;
    float* ws  = (float*)d_ws;
    (void)in_sizes; (void)n_in; (void)out_size;

    const size_t fixed_bytes = (size_t)OFF_P * 4;
    int KC, SUBT;
    if (ws_size >= fixed_bytes + 64ull * 512 * 128 * 4)      { KC = 64; SUBT = 1; }
    else                                                     { KC = 8;  SUBT = 8; }
    float* P = ws + OFF_P;

    k_setup<<<1088, 256, 0, stream>>>(ws);
    k_stage1<<<dim3(KC, 8), 256, 0, stream>>>(x, ws, P, SUBT);
    k_reduce<<<256, 256, 0, stream>>>(ws, P, KC);
    k_mix<<<BB * COUTC * 64 / 256, 256, 0, stream>>>(wr, wi, ws);
    k_stage3<<<dim3(64, 8), 256, 0, stream>>>(ws, out);
}

// Round 4
// 61.999 us; speedup vs baseline: 1.5072x; 1.0875x over previous
//
#include <hip/hip_runtime.h>

// Spectral conv, fully folded:  out = Re( ((x·G) ⊙ W) · K )
// v4: G and K never touch global memory — each block rebuilds its own
// G-chunk / K-tile in LDS using libm-free Clenshaw-Curtis tables
// (Chebyshev recurrence from cos(pi/19)). 4 dispatches total.

#define NN 4096
#define BB 8

#define C1_19 0.9863613034027223   // cos(pi/19), double

// ws float offsets
#define OFF_XRE 0                  // X real [512*64]
#define OFF_XIM 32768
#define OFF_YRE 65536              // Y real [512*64]
#define OFF_YIM 98304
#define OFF_P   131072             // split-K partials [KC][512][128]

__device__ __forceinline__ float sin_rev(float r) { return __builtin_amdgcn_sinf(r); }
__device__ __forceinline__ float cos_rev(float r) { return __builtin_amdgcn_cosf(r); }

// nd[k] = cos(pi k/19); cwd[k] = CC weight (endpoints halved). No libm.
// NOTE: contains one __syncthreads; caller must sync again before using cwd.
__device__ __forceinline__ void build_tables(double* nd, double* cwd, int t) {
    if (t == 0) {
        nd[0] = 1.0; nd[1] = C1_19;
        for (int k = 2; k < 20; ++k) nd[k] = 2.0 * C1_19 * nd[k - 1] - nd[k - 2];
    }
    __syncthreads();
    if (t < 20) {
        double v = 1.0;
        for (int j = 1; j <= 9; ++j) {
            int q = (2 * j * t) % 38; if (q > 19) q = 38 - q;   // cos(2pi j t/19)
            v -= 2.0 / (4.0 * j * j - 1.0) * nd[q];
        }
        double w = 2.0 * v / 19.0;
        if (t == 0 || t == 19) w *= 0.5;
        cwd[t] = w;
    }
}

// ---------- stage 1: P[kc][bc][128] partials; per-block G chunk in LDS ----------
__global__ __launch_bounds__(256) void k_stage1(const float* __restrict__ x,
                                                float* __restrict__ P, int SUBT) {
    __shared__ double nd[20], cwd[20];
    __shared__ float qt[64][24], qc[64][24];
    __shared__ int   qn[64];
    __shared__ __align__(16) float xt[64][68];
    __shared__ __align__(16) float gt[2][64][64];
    const int t = threadIdx.x;
    const int cc = blockIdx.y;
    build_tables(nd, cwd, t);
    const int mg = t & 15, bg = t >> 4;
    float aR[4][4] = {{0.f}}, aI[4][4] = {{0.f}};
    for (int st = 0; st < SUBT; ++st) {
        const int k0 = (blockIdx.x * SUBT + st) * 64;
        __syncthreads();                       // cwd ready / prev-iter reads done
        if (t < 64) qn[t] = 0;
        __syncthreads();
        // candidate scan: row r = t>>2, strided by s = t&3 over 60 candidates
        {
            const int r = t >> 2, s = t & 3;
            const int k = k0 + r;
            const int lc = (int)floor(((double)k + 0.5) * (100.0 / 4095.0));
            for (int c = s; c < 60; c += 4) {
                int l = lc - 1 + c / 20, jn = c % 20;
                if (l >= 0 && l < 100) {
                    double tq = ((double)l + 0.5) * 0.01 + 0.005 * nd[jn];
                    double ss = tq * 4095.0;
                    int i = (int)floor(ss);
                    if (i < 0) i = 0; if (i > 4094) i = 4094;
                    double a = ss - (double)i;
                    if (a < 0.0) a = 0.0; if (a > 1.0) a = 1.0;
                    float coef = 0.f;
                    if (i == k) coef = (float)(1.0 - a);
                    else if (i == k - 1) coef = (float)a;
                    if (coef != 0.f) {
                        int slot = atomicAdd(&qn[r], 1);    // LDS atomic
                        if (slot < 24) {
                            qt[r][slot] = (float)tq;
                            qc[r][slot] = coef * (float)(0.005 * cwd[jn]);
                        }
                    }
                }
            }
        }
        // x staging (independent of lists)
#pragma unroll
        for (int it = 0; it < 4; ++it) {
            int idx = it * 256 + t;
            int row = idx >> 4, c4 = idx & 15;
            *(float4*)&xt[row][c4 * 4] =
                *(const float4*)&x[(size_t)(cc * 64 + row) * NN + k0 + c4 * 4];
        }
        __syncthreads();
        // G eval: lane-contiguous m (bank-clean writes); rows split across waves
        {
            const int m = t & 63;
            const int r0 = (t >> 6) * 16;
            for (int rr = 0; rr < 16; ++rr) {
                const int row = r0 + rr;
                const int n = qn[row] < 24 ? qn[row] : 24;
                float gr = 0.f, gi = 0.f;
                for (int s = 0; s < n; ++s) {
                    double ph = -(double)m * (double)qt[row][s];  // phase/2pi
                    ph -= floor(ph);
                    float rf = (float)ph;
                    gr += qc[row][s] * cos_rev(rf);
                    gi += qc[row][s] * sin_rev(rf);
                }
                gt[0][row][m] = gr;
                gt[1][row][m] = gi;
            }
        }
        __syncthreads();
        // compute 64bc x 64m x 64k
        for (int kq = 0; kq < 16; ++kq) {
            float4 xv[4];
#pragma unroll
            for (int p = 0; p < 4; ++p)
                xv[p] = *(const float4*)&xt[bg * 4 + p][kq * 4];
#pragma unroll
            for (int mm = 0; mm < 4; ++mm) {
                const float4 gr = *(const float4*)&gt[0][kq * 4 + mm][mg * 4];
                const float4 gi = *(const float4*)&gt[1][kq * 4 + mm][mg * 4];
#pragma unroll
                for (int p = 0; p < 4; ++p) {
                    const float xm = (mm == 0) ? xv[p].x : (mm == 1) ? xv[p].y
                                   : (mm == 2) ? xv[p].z : xv[p].w;
                    aR[p][0] += xm * gr.x; aR[p][1] += xm * gr.y;
                    aR[p][2] += xm * gr.z; aR[p][3] += xm * gr.w;
                    aI[p][0] += xm * gi.x; aI[p][1] += xm * gi.y;
                    aI[p][2] += xm * gi.z; aI[p][3] += xm * gi.w;
                }
            }
        }
    }
#pragma unroll
    for (int p = 0; p < 4; ++p) {
        const size_t row = (size_t)blockIdx.x * 512 + cc * 64 + bg * 4 + p;
        float4 vr, vi;
        vr.x = aR[p][0]; vr.y = aR[p][1]; vr.z = aR[p][2]; vr.w = aR[p][3];
        vi.x = aI[p][0]; vi.y = aI[p][1]; vi.z = aI[p][2]; vi.w = aI[p][3];
        *(float4*)&P[row * 128 + mg * 4]      = vr;
        *(float4*)&P[row * 128 + 64 + mg * 4] = vi;
    }
}

// ---------- reduce: X = sum_kc P[kc]; 512 blocks, 8 kc-groups ----------
__global__ __launch_bounds__(256) void k_reduce(float* __restrict__ ws,
                                                const float* __restrict__ P, int KC) {
    __shared__ float4 red[8][32];
    const int t = threadIdx.x;
    const int grp = t >> 5, o = t & 31;
    const int out_id = blockIdx.x * 32 + o;        // 16384 float4 outputs
    const float4* P4 = (const float4*)P;
    const int kpg = KC >> 3;
    float4 s = {0.f, 0.f, 0.f, 0.f};
    for (int kk = 0; kk < kpg; ++kk) {
        float4 v = P4[(size_t)(grp * kpg + kk) * 16384 + out_id];
        s.x += v.x; s.y += v.y; s.z += v.z; s.w += v.w;
    }
    red[grp][o] = s;
    __syncthreads();
    if (t < 32) {
        float4 r = red[0][t];
#pragma unroll
        for (int g = 1; g < 8; ++g) {
            float4 v = red[g][t];
            r.x += v.x; r.y += v.y; r.z += v.z; r.w += v.w;
        }
        int oid = blockIdx.x * 32 + t;
        int bc = oid >> 5, c4 = oid & 31;
        if (c4 < 16) *(float4*)&ws[OFF_XRE + (size_t)bc * 64 + c4 * 4] = r;
        else         *(float4*)&ws[OFF_XIM + (size_t)bc * 64 + (c4 - 16) * 4] = r;
    }
}

// ---------- mix: Y[b][o][m] = sum_i X[b][i][m] * (Wr + iWi)[i][o][m] ----------
__global__ __launch_bounds__(256) void k_mix(const float* __restrict__ wr,
                                             const float* __restrict__ wi,
                                             float* __restrict__ ws) {
    int idx = blockIdx.x * 256 + threadIdx.x;   // b*4096 + o*64 + m
    int m = idx & 63, o = (idx >> 6) & 63, b = idx >> 12;
    float yr = 0.f, yi = 0.f;
#pragma unroll 4
    for (int i = 0; i < 64; ++i) {
        float xr = ws[OFF_XRE + (size_t)(b * 64 + i) * 64 + m];
        float xi = ws[OFF_XIM + (size_t)(b * 64 + i) * 64 + m];
        float a = wr[(size_t)(i * 64 + o) * 64 + m];
        float c = wi[(size_t)(i * 64 + o) * 64 + m];
        yr += xr * a - xi * c;
        yi += xr * c + xi * a;
    }
    ws[OFF_YRE + idx] = yr;
    ws[OFF_YIM + idx] = yi;
}

// ---------- stage 3: out = Re(Y·K); per-block K tile + Y tile in LDS ----------
__global__ __launch_bounds__(256) void k_stage3(const float* __restrict__ ws,
                                                float* __restrict__ out) {
    __shared__ double nd[20], cwd[20];
    __shared__ double qf[64][16];
    __shared__ float  qw[64][16];
    __shared__ int    qn[64];
    __shared__ __align__(16) float kt[2][64][64];
    __shared__ __align__(16) float yt[2][64][68];
    const int t = threadIdx.x;
    const int jt = blockIdx.x, pc = blockIdx.y;
    build_tables(nd, cwd, t);
    if (t < 64) qn[t] = 0;
    __syncthreads();
    // K candidate scan: m = t>>2, strided s = t&3; segments l=49..51 only
    {
        const int m = t >> 2, s = t & 3;
        for (int c = s; c < 60; c += 4) {
            int l = 49 + c / 20, kk = c % 20;
            double fc = -2048.0 + ((double)l + 0.5) * 40.95;
            double fq = fc + 20.475 * nd[kk];
            double au = fabs(fq - (double)m);
            if (au < 1.0) {
                int slot = atomicAdd(&qn[m], 1);
                if (slot < 16) {
                    qf[m][slot] = fq;
                    qw[m][slot] = (float)((1.0 - au) * 20.475 * cwd[kk]);
                }
            }
        }
    }
    // stage Y tile (64 pairs x 64 m x {re,im})
#pragma unroll
    for (int it = 0; it < 8; ++it) {
        int idx = it * 256 + t;
        int part = idx >> 10, rem = idx & 1023;
        int row = rem >> 4, c4 = rem & 15;
        const size_t src = (part ? OFF_YIM : OFF_YRE) + (size_t)(pc * 64 + row) * 64 + c4 * 4;
        *(float4*)&yt[part][row][c4 * 4] = *(const float4*)&ws[src];
    }
    __syncthreads();
    // K eval: lane-contiguous j (bank-clean); m-rows split across waves
    {
        const int jl = t & 63;
        const double tj = (double)(jt * 64 + jl) / 4095.0;
        const int m0r = (t >> 6) * 16;
        for (int rr = 0; rr < 16; ++rr) {
            const int m = m0r + rr;
            const int n = qn[m] < 16 ? qn[m] : 16;
            float ar = 0.f, ai = 0.f;
            for (int s = 0; s < n; ++s) {
                double ph = qf[m][s] * tj;      // phase/2pi
                ph -= floor(ph);
                float rf = (float)ph;
                ar += qw[m][s] * cos_rev(rf);
                ai += qw[m][s] * sin_rev(rf);
            }
            kt[0][m][jl] = ar;
            kt[1][m][jl] = ai;
        }
    }
    __syncthreads();
    const int jg = t & 15, pg = t >> 4;
    float acc[4][4] = {{0.f}};
    for (int m0 = 0; m0 < 64; m0 += 4) {
        float yr[4][4], yi[4][4];
#pragma unroll
        for (int p = 0; p < 4; ++p) {
            float4 a = *(const float4*)&yt[0][pg * 4 + p][m0];
            float4 b = *(const float4*)&yt[1][pg * 4 + p][m0];
            yr[p][0] = a.x; yr[p][1] = a.y; yr[p][2] = a.z; yr[p][3] = a.w;
            yi[p][0] = b.x; yi[p][1] = b.y; yi[p][2] = b.z; yi[p][3] = b.w;
        }
#pragma unroll
        for (int mm = 0; mm < 4; ++mm) {
            const float4 kr = *(const float4*)&kt[0][m0 + mm][jg * 4];
            const float4 ki = *(const float4*)&kt[1][m0 + mm][jg * 4];
#pragma unroll
            for (int p = 0; p < 4; ++p) {
                acc[p][0] += yr[p][mm] * kr.x - yi[p][mm] * ki.x;
                acc[p][1] += yr[p][mm] * kr.y - yi[p][mm] * ki.y;
                acc[p][2] += yr[p][mm] * kr.z - yi[p][mm] * ki.z;
                acc[p][3] += yr[p][mm] * kr.w - yi[p][mm] * ki.w;
            }
        }
    }
#pragma unroll
    for (int p = 0; p < 4; ++p) {
        float4 r;
        r.x = acc[p][0]; r.y = acc[p][1]; r.z = acc[p][2]; r.w = acc[p][3];
        *(float4*)&out[(size_t)(pc * 64 + pg * 4 + p) * NN + jt * 64 + jg * 4] = r;
    }
}

extern "C" void kernel_launch(void* const* d_in, const int* in_sizes, int n_in,
                              void* d_out, int out_size, void* d_ws, size_t ws_size,
                              hipStream_t stream) {
    const float* x  = (const float*)d_in[0];
    const float* wr = (const float*)d_in[1];
    const float* wi = (const float*)d_in[2];
    float* out = (float*)d_out;
    float* ws  = (float*)d_ws;
    (void)in_sizes; (void)n_in; (void)out_size;

    int KC, SUBT;
    if (ws_size >= ((size_t)OFF_P + 64ull * 512 * 128) * 4) { KC = 64; SUBT = 1; }
    else                                                    { KC = 8;  SUBT = 8; }
    float* P = ws + OFF_P;

    k_stage1<<<dim3(KC, 8), 256, 0, stream>>>(x, P, SUBT);
    k_reduce<<<512, 256, 0, stream>>>(ws, P, KC);
    k_mix<<<128, 256, 0, stream>>>(wr, wi, ws);
    k_stage3<<<dim3(64, 8), 256, 0, stream>>>(ws, out);
}

// Round 5
// 50.303 us; speedup vs baseline: 1.8576x; 1.2325x over previous
//
#include <hip/hip_runtime.h>

// Spectral conv, factorized like the reference:
//   xq = interp(x -> 2000 cheb nodes)          (per-block window in LDS)
//   X  = xq @ E,  E[s][m] = wq_s exp(-2pi i m tq_s)   (E built in LDS, 40 s/block)
//   Y  = channel-mix(X, W)
//   Z[p][s] = sum_m Y[p][m] hat_s(m)           (only 33 f-nodes have hat weight)
//   out = sum_s Re(Z[p][s] * wf_s exp(+2pi i fq_s t_j))
// v5: 2000-node GEMM (half the FLOPs of v4), rank-33 ICFT (2x fewer FLOPs),
// trig count per block ~20x lower so f64 phase math is negligible.

#define NN 4096
#define C1_19 0.9863613034027223   // cos(pi/19)

// ws float offsets
#define OFF_XRE 0                  // X real [512*64]
#define OFF_XIM 32768
#define OFF_Z   65536              // Z [2][512][40]
#define OFF_P   106496             // partials [50][512][128]

#define NS3     33                 // contributing f-nodes for ICFT
#define NSP     40                 // padded

__device__ __forceinline__ float sin_rev(float r) { return __builtin_amdgcn_sinf(r); }
__device__ __forceinline__ float cos_rev(float r) { return __builtin_amdgcn_cosf(r); }

// nd[k] = cos(pi k/19); cwd[k] = CC weight (endpoints halved). No libm.
// Contains one __syncthreads; caller must sync again before using cwd.
__device__ __forceinline__ void build_tables(double* nd, double* cwd, int t) {
    if (t == 0) {
        nd[0] = 1.0; nd[1] = C1_19;
        for (int k = 2; k < 20; ++k) nd[k] = 2.0 * C1_19 * nd[k - 1] - nd[k - 2];
    }
    __syncthreads();
    if (t < 20) {
        double v = 1.0;
        for (int j = 1; j <= 9; ++j) {
            int q = (2 * j * t) % 38; if (q > 19) q = 38 - q;   // cos(2pi j t/19)
            v -= 2.0 / (4.0 * j * j - 1.0) * nd[q];
        }
        double w = 2.0 * v / 19.0;
        if (t == 0 || t == 19) w *= 0.5;
        cwd[t] = w;
    }
}

// canonical ICFT node list: s -> (l, k), 33 nodes with hat support in (-1,64)
__device__ __forceinline__ void icft_node(int s, int* l, int* k) {
    *l = (s < 2) ? 49 : (s < 22 ? 50 : 51);
    *k = (s < 2) ? s : (s < 22 ? s - 2 : s - 13);
}

// ---------- stage 1: P[sc][bc][128] partials over 40-node s-chunks ----------
// grid (50, 8): sc = 40 cheb nodes (2 segments), cc = 64 bc rows.
__global__ __launch_bounds__(256) void k_stage1(const float* __restrict__ x,
                                                float* __restrict__ P) {
    __shared__ double nd[20], cwd[20];
    __shared__ float qt[40], qa[40], qw[40];
    __shared__ int   qi[40];
    __shared__ __align__(16) float xw[64][93];    // 92-col window, odd stride
    __shared__ __align__(16) float e[2][40][64];
    __shared__ __align__(16) float xqT[40][64];   // [node][bc-row]
    const int t = threadIdx.x;
    const int sc = blockIdx.x, cc = blockIdx.y;
    build_tables(nd, cwd, t);
    __syncthreads();
    int i0 = (int)(81.9 * (double)sc) - 2;        // min col = floor(81.9*sc)
    if (i0 < 0) i0 = 0;
    i0 &= ~3;
    if (i0 > 4004) i0 = 4004;                     // window always in-bounds
    if (t < 40) {
        int l = 2 * sc + (t >= 20), jn = t % 20;
        double tq = 0.005 * ((double)(2 * l + 1) + nd[jn]);
        double sf = tq * 4095.0;
        int i = (int)sf; if (i > 4094) i = 4094;
        double a = sf - (double)i;
        if (a < 0.0) a = 0.0; if (a > 1.0) a = 1.0;
        qi[t] = i - i0;
        qa[t] = (float)a;
        qt[t] = (float)tq;
        qw[t] = (float)(0.005 * cwd[jn]);
    }
    // stage x window: 64 rows x 92 cols (f4 global loads, scalar LDS writes)
    for (int idx = t; idx < 64 * 23; idx += 256) {
        int row = idx / 23, c4 = idx % 23;
        float4 v = *(const float4*)&x[(size_t)(cc * 64 + row) * NN + i0 + c4 * 4];
        float* d = &xw[row][c4 * 4];
        d[0] = v.x; d[1] = v.y; d[2] = v.z; d[3] = v.w;
    }
    __syncthreads();
    // E[s][m] = wq_s * exp(-2pi i m tq_s)
    for (int idx = t; idx < 40 * 64; idx += 256) {
        int s = idx >> 6, m = idx & 63;
        double r = -(double)m * (double)qt[s];
        r -= floor(r);
        float fr = (float)r;
        e[0][s][m] = qw[s] * cos_rev(fr);
        e[1][s][m] = qw[s] * sin_rev(fr);
    }
    // interp: xqT[q][r] (lanes r consecutive: conflict-free writes)
    for (int idx = t; idx < 40 * 64; idx += 256) {
        int q = idx >> 6, r = idx & 63;
        float a = qa[q];
        xqT[q][r] = (1.f - a) * xw[r][qi[q]] + a * xw[r][qi[q] + 1];
    }
    __syncthreads();
    // GEMM: 64bc x 64m x 40s
    const int mg = t & 15, bg = t >> 4;
    float aR[4][4] = {{0.f}}, aI[4][4] = {{0.f}};
    for (int s = 0; s < 40; ++s) {
        const float4 xv = *(const float4*)&xqT[s][bg * 4];
        const float4 er = *(const float4*)&e[0][s][mg * 4];
        const float4 ei = *(const float4*)&e[1][s][mg * 4];
#pragma unroll
        for (int p = 0; p < 4; ++p) {
            const float xm = (p == 0) ? xv.x : (p == 1) ? xv.y : (p == 2) ? xv.z : xv.w;
            aR[p][0] += xm * er.x; aR[p][1] += xm * er.y;
            aR[p][2] += xm * er.z; aR[p][3] += xm * er.w;
            aI[p][0] += xm * ei.x; aI[p][1] += xm * ei.y;
            aI[p][2] += xm * ei.z; aI[p][3] += xm * ei.w;
        }
    }
#pragma unroll
    for (int p = 0; p < 4; ++p) {
        const size_t row = (size_t)sc * 512 + cc * 64 + bg * 4 + p;
        float4 vr, vi;
        vr.x = aR[p][0]; vr.y = aR[p][1]; vr.z = aR[p][2]; vr.w = aR[p][3];
        vi.x = aI[p][0]; vi.y = aI[p][1]; vi.z = aI[p][2]; vi.w = aI[p][3];
        *(float4*)&P[row * 128 + mg * 4]      = vr;
        *(float4*)&P[row * 128 + 64 + mg * 4] = vi;
    }
}

// ---------- reduce: X = sum_sc P[sc] (50 chunks, 2 groups of 25) ----------
__global__ __launch_bounds__(256) void k_reduce(float* __restrict__ ws,
                                                const float* __restrict__ P) {
    __shared__ float4 red[2][128];
    const int t = threadIdx.x;
    const int grp = t >> 7, o = t & 127;
    const int oid = blockIdx.x * 128 + o;          // 16384 float4 outputs
    const float4* P4 = (const float4*)P;
    float4 s = {0.f, 0.f, 0.f, 0.f};
    for (int kk = 0; kk < 25; ++kk) {
        float4 v = P4[(size_t)(grp * 25 + kk) * 16384 + oid];
        s.x += v.x; s.y += v.y; s.z += v.z; s.w += v.w;
    }
    red[grp][o] = s;
    __syncthreads();
    if (t < 128) {
        float4 a = red[0][t], b = red[1][t];
        float4 r; r.x = a.x + b.x; r.y = a.y + b.y; r.z = a.z + b.z; r.w = a.w + b.w;
        int od = blockIdx.x * 128 + t;
        int bc = od >> 5, c4 = od & 31;
        if (c4 < 16) *(float4*)&ws[OFF_XRE + (size_t)bc * 64 + c4 * 4] = r;
        else         *(float4*)&ws[OFF_XIM + (size_t)bc * 64 + (c4 - 16) * 4] = r;
    }
}

// ---------- mixZ: Y = channel mix; Z[p][s] = sum_m Y[p][m] hat_s(m) ----------
// grid 64: b = blk>>3, og = blk&7 (8 output channels each)
__global__ __launch_bounds__(256) void k_mixZ(const float* __restrict__ wr,
                                              const float* __restrict__ wi,
                                              float* __restrict__ ws) {
    __shared__ double nd[20], cwd[20];
    __shared__ __align__(16) float xt[2][64][64];
    __shared__ float yt[2][8][64];
    __shared__ float sw0[NS3], sw1[NS3];
    __shared__ int   si0[NS3], si1[NS3];
    const int t = threadIdx.x;
    const int b = blockIdx.x >> 3, og = blockIdx.x & 7;
    build_tables(nd, cwd, t);
    __syncthreads();
    if (t < NS3) {
        int l, k; icft_node(t, &l, &k);
        double fq = -2048.0 + ((double)l + 0.5) * 40.95 + 20.475 * nd[k];
        int m0 = (int)floor(fq);
        float fr = (float)(fq - (double)m0);
        sw0[t] = (m0 >= 0 && m0 <= 63) ? (1.f - fr) : 0.f;
        sw1[t] = (m0 + 1 >= 0 && m0 + 1 <= 63) ? fr : 0.f;
        si0[t] = min(max(m0, 0), 63);
        si1[t] = min(max(m0 + 1, 0), 63);
    }
    for (int idx = t; idx < 2048; idx += 256) {    // stage X[b] tile (32KB)
        int part = idx >> 10, rem = idx & 1023;
        int row = rem >> 4, c4 = rem & 15;
        *(float4*)&xt[part][row][c4 * 4] =
            *(const float4*)&ws[(part ? OFF_XIM : OFF_XRE) + (size_t)(b * 64 + row) * 64 + c4 * 4];
    }
    __syncthreads();
    const int m = t & 63;
#pragma unroll
    for (int pp = 0; pp < 2; ++pp) {
        const int p = (t >> 6) * 2 + pp;           // 0..7
        const int o = og * 8 + p;
        float yr = 0.f, yi = 0.f;
#pragma unroll 4
        for (int i = 0; i < 64; ++i) {
            float xr = xt[0][i][m], xi = xt[1][i][m];
            float a = wr[((size_t)i * 64 + o) * 64 + m];
            float c = wi[((size_t)i * 64 + o) * 64 + m];
            yr += xr * a - xi * c;
            yi += xr * c + xi * a;
        }
        yt[0][p][m] = yr;
        yt[1][p][m] = yi;
    }
    __syncthreads();
    for (int idx = t; idx < 2 * 8 * NSP; idx += 256) {
        int part = idx / (8 * NSP), rem = idx % (8 * NSP);
        int p = rem / NSP, s = rem % NSP;
        float z = 0.f;
        if (s < NS3)
            z = sw0[s] * yt[part][p][si0[s]] + sw1[s] * yt[part][p][si1[s]];
        ws[OFF_Z + (size_t)part * 512 * NSP + ((size_t)b * 64 + og * 8 + p) * NSP + s] = z;
    }
}

// ---------- stage 3: out[p][j] = sum_s Re(Z[p][s] * wf_s e^{2pi i fq_s t_j}) ----------
// grid (64 jt, 8 pc)
__global__ __launch_bounds__(256) void k_stage3(const float* __restrict__ ws,
                                                float* __restrict__ out) {
    __shared__ double nd[20], cwd[20];
    __shared__ double sfq[NS3];
    __shared__ float  swf[NS3];
    __shared__ __align__(16) float zt[2][64][41];  // odd stride: 2-way max
    __shared__ __align__(16) float e2[2][NSP][64];
    const int t = threadIdx.x;
    const int jt = blockIdx.x, pc = blockIdx.y;
    build_tables(nd, cwd, t);
    __syncthreads();
    if (t < NS3) {
        int l, k; icft_node(t, &l, &k);
        sfq[t] = -2048.0 + ((double)l + 0.5) * 40.95 + 20.475 * nd[k];
        swf[t] = (float)(20.475 * cwd[k]);
    }
    for (int idx = t; idx < 2 * 64 * NSP; idx += 256) {   // stage Z tile
        int part = idx / (64 * NSP), rem = idx % (64 * NSP);
        int row = rem / NSP, s = rem % NSP;
        zt[part][row][s] =
            ws[OFF_Z + (size_t)part * 512 * NSP + ((size_t)pc * 64 + row) * NSP + s];
    }
    __syncthreads();
    const double inv4095 = 1.0 / 4095.0;
    for (int idx = t; idx < NSP * 64; idx += 256) {       // E2 build
        int s = idx >> 6, jl = idx & 63;
        float cr = 0.f, ci = 0.f;
        if (s < NS3) {
            double ph = sfq[s] * ((double)(jt * 64 + jl) * inv4095);
            ph -= floor(ph);
            float fr = (float)ph;
            cr = swf[s] * cos_rev(fr);
            ci = swf[s] * sin_rev(fr);
        }
        e2[0][s][jl] = cr;
        e2[1][s][jl] = ci;
    }
    __syncthreads();
    const int jg = t & 15, pg = t >> 4;
    float acc[4][4] = {{0.f}};
    for (int s0 = 0; s0 < NSP; s0 += 8) {
        float zr[4][8], zi[4][8];
#pragma unroll
        for (int p = 0; p < 4; ++p)
#pragma unroll
            for (int u = 0; u < 8; ++u) {
                zr[p][u] = zt[0][pg * 4 + p][s0 + u];
                zi[p][u] = zt[1][pg * 4 + p][s0 + u];
            }
#pragma unroll
        for (int u = 0; u < 8; ++u) {
            const float4 er = *(const float4*)&e2[0][s0 + u][jg * 4];
            const float4 ei = *(const float4*)&e2[1][s0 + u][jg * 4];
#pragma unroll
            for (int p = 0; p < 4; ++p) {
                acc[p][0] += zr[p][u] * er.x - zi[p][u] * ei.x;
                acc[p][1] += zr[p][u] * er.y - zi[p][u] * ei.y;
                acc[p][2] += zr[p][u] * er.z - zi[p][u] * ei.z;
                acc[p][3] += zr[p][u] * er.w - zi[p][u] * ei.w;
            }
        }
    }
#pragma unroll
    for (int p = 0; p < 4; ++p) {
        float4 r;
        r.x = acc[p][0]; r.y = acc[p][1]; r.z = acc[p][2]; r.w = acc[p][3];
        *(float4*)&out[(size_t)(pc * 64 + pg * 4 + p) * NN + jt * 64 + jg * 4] = r;
    }
}

extern "C" void kernel_launch(void* const* d_in, const int* in_sizes, int n_in,
                              void* d_out, int out_size, void* d_ws, size_t ws_size,
                              hipStream_t stream) {
    const float* x  = (const float*)d_in[0];
    const float* wr = (const float*)d_in[1];
    const float* wi = (const float*)d_in[2];
    float* out = (float*)d_out;
    float* ws  = (float*)d_ws;
    (void)in_sizes; (void)n_in; (void)out_size; (void)ws_size;   // needs ~13.5 MB

    float* P = ws + OFF_P;
    k_stage1<<<dim3(50, 8), 256, 0, stream>>>(x, P);
    k_reduce<<<128, 256, 0, stream>>>(ws, P);
    k_mixZ<<<64, 256, 0, stream>>>(wr, wi, ws);
    k_stage3<<<dim3(64, 8), 256, 0, stream>>>(ws, out);
}